// Round 5
// baseline (1548.033 us; speedup 1.0000x reference)
//
#include <hip/hip_runtime.h>

#define HIDDEN 51
#define LSEQ 1000
#define UNROLL 8    // steps buffered between butterfly/store groups

typedef float v2f __attribute__((ext_vector_type(2)));

// Branch-free tanh: tanh(v) = 1 - 2/(exp2(2*log2e*v)+1). Saturates to +/-1.
__device__ __forceinline__ float fast_tanh(float v) {
    float e = __builtin_amdgcn_exp2f(v * 2.885390081777927f);  // 2*log2(e)
    float r = __builtin_amdgcn_rcpf(e + 1.0f);
    return fmaf(-2.0f, r, 1.0f);
}

// R5 = R4 + sched_barrier(0) fence to FORCE the full-depth LDS prefetch.
// Evidence: R4's prefetch won (535->488) but VGPR_Count stayed 128 -- the
// register allocator re-serialized hv[13] into few registers, so only a
// few ds_read_b128 stay in flight and ~600cy/step of LDS latency remains
// exposed. The fence pins all 13 loads before any consumer: loads can't
// sink, FMAs can't hoist, so all 13 float4 results are live at once ->
// allocator must give ~180 VGPR (+208 AGPR = 388 <= 512, still 1
// wave/SIMD, no spill). Compiler's own fine-grained lgkmcnt then overlaps
// FMA issue with the read-return drain.
// Multi-wave structures (R1/R2/R3) all regressed: per-step cross-wave
// exchange costs more than the issue width it buys on a 1000-step serial
// recurrence. Single-wave + deep ILP is the right shape.
__global__ __launch_bounds__(64, 1) void lstm_seq_kernel(
    const float* __restrict__ x,
    const float* __restrict__ W_w,
    const float* __restrict__ W_b,
    const float* __restrict__ U_w,
    const float* __restrict__ U_b,
    const float* __restrict__ lin_w,
    const float* __restrict__ lin_b,
    float* __restrict__ out)
{
    __shared__ __attribute__((aligned(16))) float hb[64];  // h broadcast

    const int b    = blockIdx.x;
    const int lane = threadIdx.x;        // 0..63
    const bool active = lane < HIDDEN;   // lanes 51..63 produce exact zeros
    const int m = active ? lane : 0;

    float ww[4], bbias[4];
#pragma unroll
    for (int g = 0; g < 4; ++g) {
        const int row = m + g * HIDDEN;
        ww[g]    = active ? W_w[row] : 0.f;
        bbias[g] = active ? (W_b[row] + U_b[row]) : 0.f;
    }
    const float lw = active ? lin_w[m] : 0.f;
    const float lb = lin_b[0];

    // U packed over k-pairs: Up[g][j] = {U[row][2j], U[row][2j+1]}, j<26.
    // k==51 is a zero pad (matches hb[51]==0 from lane 51's h==0).
    v2f Up[4][26];
#pragma unroll
    for (int j = 0; j < 26; ++j) {
        const int k0 = 2 * j, k1 = 2 * j + 1;
#pragma unroll
        for (int g = 0; g < 4; ++g) {
            const int row = m + g * HIDDEN;
            v2f u;
            u.x = (active && k0 < HIDDEN) ? U_w[row * HIDDEN + k0] : 0.f;
            u.y = (active && k1 < HIDDEN) ? U_w[row * HIDDEN + k1] : 0.f;
            Up[g][j] = u;
        }
    }

    float h = 0.f, c = 0.f;
    const float* __restrict__ xrow = x + (long)b * LSEQ;
    float* __restrict__ orow = out + (long)b * LSEQ;

    hb[lane] = 0.f;                       // single wave: in-order LDS pipe
    __builtin_amdgcn_wave_barrier();      // compile-time ordering insurance

    for (int T = 0; T < LSEQ; T += UNROLL) {
        float xg[UNROLL], rb[UNROLL];
#pragma unroll
        for (int s = 0; s < UNROLL; ++s) xg[s] = xrow[T + s];  // uniform

#pragma unroll
        for (int s = 0; s < UNROLL; ++s) {
            // Full-depth prefetch: all 13 same-address b128 broadcasts
            // issued back-to-back (conflict-free), THEN the fence. Loads
            // cannot sink below it; consumers cannot hoist above it ->
            // 52 VGPRs of h live at once, 13 reads in flight.
            float4 hv[13];
#pragma unroll
            for (int q = 0; q < 13; ++q) hv[q] = *(const float4*)&hb[q * 4];
            __builtin_amdgcn_sched_barrier(0);

            // Accumulators seeded with x*W + (W_b+U_b): tail = pure hsum.
            v2f a0 = {fmaf(xg[s], ww[0], bbias[0]), 0.f};
            v2f a1 = {fmaf(xg[s], ww[1], bbias[1]), 0.f};
            v2f a2 = {fmaf(xg[s], ww[2], bbias[2]), 0.f};
            v2f a3 = {fmaf(xg[s], ww[3], bbias[3]), 0.f};
#pragma unroll
            for (int q = 0; q < 13; ++q) {
                const v2f hlo = {hv[q].x, hv[q].y};
                const v2f hhi = {hv[q].z, hv[q].w};
                a0 = __builtin_elementwise_fma(hlo, Up[0][2 * q], a0);
                a1 = __builtin_elementwise_fma(hlo, Up[1][2 * q], a1);
                a2 = __builtin_elementwise_fma(hlo, Up[2][2 * q], a2);
                a3 = __builtin_elementwise_fma(hlo, Up[3][2 * q], a3);
                a0 = __builtin_elementwise_fma(hhi, Up[0][2 * q + 1], a0);
                a1 = __builtin_elementwise_fma(hhi, Up[1][2 * q + 1], a1);
                a2 = __builtin_elementwise_fma(hhi, Up[2][2 * q + 1], a2);
                a3 = __builtin_elementwise_fma(hhi, Up[3][2 * q + 1], a3);
            }
            const float gi = a0.x + a0.y;
            const float gf = a1.x + a1.y;
            const float gg = a2.x + a2.y;
            const float go = a3.x + a3.y;

            // NOTE: faithful to reference -- no sigmoid on gates.
            c = fmaf(gf, c, gi * gg);
            h = go * fast_tanh(c);        // inactive lanes stay exactly 0

            __builtin_amdgcn_wave_barrier();  // reads above precede write
            hb[lane] = h;
            __builtin_amdgcn_wave_barrier();  // write precedes next reads
            rb[s] = h * lw;
        }

        // 8 independent butterflies -- swizzle latencies overlap across s.
#pragma unroll
        for (int s = 0; s < UNROLL; ++s) {
#pragma unroll
            for (int off = 32; off > 0; off >>= 1)
                rb[s] += __shfl_xor(rb[s], off, 64);
        }
        if (lane == 0) {
            float4 o0 = {rb[0] + lb, rb[1] + lb, rb[2] + lb, rb[3] + lb};
            float4 o1 = {rb[4] + lb, rb[5] + lb, rb[6] + lb, rb[7] + lb};
            *(float4*)&orow[T]     = o0;   // orow 16B-aligned (b*4000 bytes)
            *(float4*)&orow[T + 4] = o1;
        }
    }
}

extern "C" void kernel_launch(void* const* d_in, const int* in_sizes, int n_in,
                              void* d_out, int out_size, void* d_ws, size_t ws_size,
                              hipStream_t stream) {
    const float* x     = (const float*)d_in[0];
    const float* W_w   = (const float*)d_in[1];
    const float* W_b   = (const float*)d_in[2];
    const float* U_w   = (const float*)d_in[3];
    const float* U_b   = (const float*)d_in[4];
    const float* lin_w = (const float*)d_in[5];
    const float* lin_b = (const float*)d_in[6];
    // d_in[7] = future (static 0; out_size == B*LSEQ)
    float* out = (float*)d_out;

    const int B = in_sizes[0] / LSEQ;  // 1024
    lstm_seq_kernel<<<dim3(B), dim3(64), 0, stream>>>(
        x, W_w, W_b, U_w, U_b, lin_w, lin_b, out);
}

// Round 6
// 428.764 us; speedup vs baseline: 3.6105x; 3.6105x over previous
//
#include <hip/hip_runtime.h>

#define HIDDEN 51
#define LSEQ 1000
#define UNROLL 8    // steps buffered between butterfly/store groups

typedef _Float16 half2_t __attribute__((ext_vector_type(2)));

#if __has_builtin(__builtin_amdgcn_fdot2)
#define FDOT2(a, b, c) __builtin_amdgcn_fdot2((a), (b), (c), false)
#else
#define FDOT2(a, b, c) fmaf((float)(a).y, (float)(b).y, \
                       fmaf((float)(a).x, (float)(b).x, (c)))
#endif

// Branch-free tanh: tanh(v) = 1 - 2/(exp2(2*log2e*v)+1). Saturates to +/-1.
__device__ __forceinline__ float fast_tanh(float v) {
    float e = __builtin_amdgcn_exp2f(v * 2.885390081777927f);  // 2*log2(e)
    float r = __builtin_amdgcn_rcpf(e + 1.0f);
    return fmaf(-2.0f, r, 1.0f);
}

// R6: U and the h-broadcast in packed f16, consumed by v_dot2_f32_f16.
// Evidence trail: R5's hard fence spilled U to scratch (VGPR 256, FETCH
// 4.3MB->2.37GB) -- proving U's 208-fp32 footprint never fit the arch
// file; R0/R4's VGPR=128 means U lived in AGPRs with per-use staging
// (explains VALUBusy ~570cy/step vs 208cy of pure pk_fma issue).
// Fix the footprint, not the schedule:
//  - U as f16 k-pairs: 104 VGPRs (one dword/pair) -> ~170 total regs,
//    everything arch-VGPR-resident, zero staging, zero spill.
//  - h broadcast stored in LDS as f16: 7 b128 reads/step (was 13), each
//    returning 8 h values already packed for dot2.
//  - dot2 accumulates in fp32; f16xf16 products are exact in fp32, so
//    only input-rounding error (~4e-4/gate) is added. h/c recurrence and
//    the output projection stay fp32.
// Multi-wave structures (R1/R2/R3) all regressed; single-wave + small
// footprint + deep ILP is the shape.
__global__ __launch_bounds__(64, 1) void lstm_seq_kernel(
    const float* __restrict__ x,
    const float* __restrict__ W_w,
    const float* __restrict__ W_b,
    const float* __restrict__ U_w,
    const float* __restrict__ U_b,
    const float* __restrict__ lin_w,
    const float* __restrict__ lin_b,
    float* __restrict__ out)
{
    __shared__ __attribute__((aligned(16))) _Float16 hb16[64];  // h bcast (f16)

    const int b    = blockIdx.x;
    const int lane = threadIdx.x;        // 0..63
    const bool active = lane < HIDDEN;   // lanes 51..63 produce exact zeros
    const int m = active ? lane : 0;

    float ww[4], bbias[4];
#pragma unroll
    for (int g = 0; g < 4; ++g) {
        const int row = m + g * HIDDEN;
        ww[g]    = active ? W_w[row] : 0.f;
        bbias[g] = active ? (W_b[row] + U_b[row]) : 0.f;
    }
    const float lw = active ? lin_w[m] : 0.f;
    const float lb = lin_b[0];

    // U packed as f16 k-pairs: Up[g][j] = {U[row][2j], U[row][2j+1]}, j<26.
    // One dword per pair -> 104 VGPRs total. k>=51 zero-padded (matches
    // hb16[51..63]==0 from inactive lanes' h==0).
    half2_t Up[4][26];
#pragma unroll
    for (int j = 0; j < 26; ++j) {
        const int k0 = 2 * j, k1 = 2 * j + 1;
#pragma unroll
        for (int g = 0; g < 4; ++g) {
            const int row = m + g * HIDDEN;
            half2_t u;
            u.x = (_Float16)((active && k0 < HIDDEN) ? U_w[row * HIDDEN + k0] : 0.f);
            u.y = (_Float16)((active && k1 < HIDDEN) ? U_w[row * HIDDEN + k1] : 0.f);
            Up[g][j] = u;
        }
    }

    float h = 0.f, c = 0.f;
    const float* __restrict__ xrow = x + (long)b * LSEQ;
    float* __restrict__ orow = out + (long)b * LSEQ;

    hb16[lane] = (_Float16)0.f;           // single wave: in-order LDS pipe
    __builtin_amdgcn_wave_barrier();      // compile-time ordering insurance

    const uint4* __restrict__ hbv = (const uint4*)hb16;  // 8 f16 per read

    for (int T = 0; T < LSEQ; T += UNROLL) {
        float xg[UNROLL], rb[UNROLL];
#pragma unroll
        for (int s = 0; s < UNROLL; ++s) xg[s] = xrow[T + s];  // uniform

#pragma unroll
        for (int s = 0; s < UNROLL; ++s) {
            // 7 same-address b128 broadcasts (conflict-free), issued up
            // front; 28 VGPRs if all live -- cheap now that U is small.
            uint4 hq[7];
#pragma unroll
            for (int q = 0; q < 7; ++q) hq[q] = hbv[q];

            // Scalar fp32 accumulators seeded with x*W + (W_b+U_b);
            // 4 independent dot2 chains, depth 26 (104cy) < issue (208cy).
            float a0 = fmaf(xg[s], ww[0], bbias[0]);
            float a1 = fmaf(xg[s], ww[1], bbias[1]);
            float a2 = fmaf(xg[s], ww[2], bbias[2]);
            float a3 = fmaf(xg[s], ww[3], bbias[3]);
#pragma unroll
            for (int q = 0; q < 7; ++q) {
                const unsigned int wds[4] = {hq[q].x, hq[q].y, hq[q].z, hq[q].w};
#pragma unroll
                for (int e = 0; e < 4; ++e) {
                    const int j = 4 * q + e;          // k-pair index
                    if (j < 26) {
                        const half2_t hp = __builtin_bit_cast(half2_t, wds[e]);
                        a0 = FDOT2(hp, Up[0][j], a0);
                        a1 = FDOT2(hp, Up[1][j], a1);
                        a2 = FDOT2(hp, Up[2][j], a2);
                        a3 = FDOT2(hp, Up[3][j], a3);
                    }
                }
            }

            // NOTE: faithful to reference -- no sigmoid on gates.
            c = fmaf(a1, c, a0 * a2);     // c = gf*c + gi*gg
            h = a3 * fast_tanh(c);        // inactive lanes stay exactly 0

            __builtin_amdgcn_wave_barrier();  // reads above precede write
            hb16[lane] = (_Float16)h;         // 2B store; recurrence stays fp32
            __builtin_amdgcn_wave_barrier();  // write precedes next reads
            rb[s] = h * lw;
        }

        // 8 independent butterflies -- swizzle latencies overlap across s.
#pragma unroll
        for (int s = 0; s < UNROLL; ++s) {
#pragma unroll
            for (int off = 32; off > 0; off >>= 1)
                rb[s] += __shfl_xor(rb[s], off, 64);
        }
        if (lane == 0) {
            float4 o0 = {rb[0] + lb, rb[1] + lb, rb[2] + lb, rb[3] + lb};
            float4 o1 = {rb[4] + lb, rb[5] + lb, rb[6] + lb, rb[7] + lb};
            *(float4*)&orow[T]     = o0;   // orow 16B-aligned (b*4000 bytes)
            *(float4*)&orow[T + 4] = o1;
        }
    }
}

extern "C" void kernel_launch(void* const* d_in, const int* in_sizes, int n_in,
                              void* d_out, int out_size, void* d_ws, size_t ws_size,
                              hipStream_t stream) {
    const float* x     = (const float*)d_in[0];
    const float* W_w   = (const float*)d_in[1];
    const float* W_b   = (const float*)d_in[2];
    const float* U_w   = (const float*)d_in[3];
    const float* U_b   = (const float*)d_in[4];
    const float* lin_w = (const float*)d_in[5];
    const float* lin_b = (const float*)d_in[6];
    // d_in[7] = future (static 0; out_size == B*LSEQ)
    float* out = (float*)d_out;

    const int B = in_sizes[0] / LSEQ;  // 1024
    lstm_seq_kernel<<<dim3(B), dim3(64), 0, stream>>>(
        x, W_w, W_b, U_w, U_b, lin_w, lin_b, out);
}

// Round 8
// 403.804 us; speedup vs baseline: 3.8336x; 1.0618x over previous
//
#include <hip/hip_runtime.h>

#define HIDDEN 51
#define LSEQ 1000
#define UNROLL 8    // steps per group (x prefetch + store granularity)

typedef _Float16 half2_t __attribute__((ext_vector_type(2)));

#if __has_builtin(__builtin_amdgcn_fdot2)
#define FDOT2(a, b, c) __builtin_amdgcn_fdot2((a), (b), (c), false)
#else
#define FDOT2(a, b, c) fmaf((float)(a).y, (float)(b).y, \
                       fmaf((float)(a).x, (float)(b).x, (c)))
#endif

// Branch-free tanh: tanh(v) = 1 - 2/(exp2(2*log2e*v)+1). Saturates to +/-1.
__device__ __forceinline__ float fast_tanh(float v) {
    float e = __builtin_amdgcn_exp2f(v * 2.885390081777927f);  // 2*log2(e)
    float r = __builtin_amdgcn_rcpf(e + 1.0f);
    return fmaf(-2.0f, r, 1.0f);
}

// One DPP-reduce level: v += dpp(v). ctrl/row_mask are template args --
// __builtin_amdgcn_update_dpp requires integer CONSTANT operands (R7's
// compile fail: runtime function args rejected). bound_ctrl=1 feeds 0 at
// row edges; masked-out rows keep old=0 -- exact for sums.
template <int CTRL, int ROW_MASK>
__device__ __forceinline__ float dpp_add(float v) {
    int s = __builtin_amdgcn_update_dpp(0, __builtin_bit_cast(int, v),
                                        CTRL, ROW_MASK, 0xf, true);
    return v + __builtin_bit_cast(float, s);
}

// Full-wave sum -> lane 63 (rocPRIM gfx9 pattern): row_shr 1/2/4/8 within
// 16-lane rows, then row_bcast15 (rows 1,3) + row_bcast31 (rows 2,3).
// 6 full-rate VALU adds, ~24cy, ZERO LDS-pipe traffic.
__device__ __forceinline__ float wave_reduce_to63(float v) {
    v = dpp_add<0x111, 0xf>(v);  // row_shr:1
    v = dpp_add<0x112, 0xf>(v);  // row_shr:2
    v = dpp_add<0x114, 0xf>(v);  // row_shr:4
    v = dpp_add<0x118, 0xf>(v);  // row_shr:8 -> lanes 15/31/47/63 = row sums
    v = dpp_add<0x142, 0xa>(v);  // row_bcast15 -> lane31+=l15, lane63+=l47
    v = dpp_add<0x143, 0xc>(v);  // row_bcast31 -> lanes 32..63 += lane31
    return v;                    // lane 63 = full sum
}

// R8 = R6 + x group-ahead prefetch + DPP projection reduce in LDS shadow.
// (R7 was this change with a compile error in the DPP helper.)
// Evidence trail: R6 (f16 U via v_dot2) 488->428, steady 404ns/step,
// VALUBusy 54% -- two stall sources every round has carried:
//  (1) cold x loads at group top: x is streamed (read once, 4MB), the
//      first seed consumes xg[0] immediately -> ~300-900cy stall per
//      group. Fix: double-buffer -- load group T+8's x at the top of
//      group T; latency amortizes over ~5000cy of work.
//  (2) __shfl_xor butterfly: 48 ds_bpermute/group on the SAME in-order
//      LDS pipe as the h broadcast, 6-deep dependent chain (~300cy) at
//      group end that can't overlap next step's reads (wave_barrier pins
//      order). Fix: DPP reduce (full-rate VALU, no LDS), done per-step
//      inside the ~120cy broadcast-read window. Store from lane 63.
// Multi-wave (R1/R2/R3) all regressed; hard fence (R5) spilled U.
// Single-wave, small footprint, deep ILP is the shape.
__global__ __launch_bounds__(64, 1) void lstm_seq_kernel(
    const float* __restrict__ x,
    const float* __restrict__ W_w,
    const float* __restrict__ W_b,
    const float* __restrict__ U_w,
    const float* __restrict__ U_b,
    const float* __restrict__ lin_w,
    const float* __restrict__ lin_b,
    float* __restrict__ out)
{
    __shared__ __attribute__((aligned(16))) _Float16 hb16[64];  // h bcast (f16)

    const int b    = blockIdx.x;
    const int lane = threadIdx.x;        // 0..63
    const bool active = lane < HIDDEN;   // lanes 51..63 produce exact zeros
    const int m = active ? lane : 0;

    float ww[4], bbias[4];
#pragma unroll
    for (int g = 0; g < 4; ++g) {
        const int row = m + g * HIDDEN;
        ww[g]    = active ? W_w[row] : 0.f;
        bbias[g] = active ? (W_b[row] + U_b[row]) : 0.f;
    }
    const float lw = active ? lin_w[m] : 0.f;
    const float lb = lin_b[0];

    // U packed as f16 k-pairs: Up[g][j] = {U[row][2j], U[row][2j+1]}, j<26.
    // One dword per pair -> 104 regs total. k>=51 zero-padded (matches
    // hb16[51..63]==0 from inactive lanes' h==0).
    half2_t Up[4][26];
#pragma unroll
    for (int j = 0; j < 26; ++j) {
        const int k0 = 2 * j, k1 = 2 * j + 1;
#pragma unroll
        for (int g = 0; g < 4; ++g) {
            const int row = m + g * HIDDEN;
            half2_t u;
            u.x = (_Float16)((active && k0 < HIDDEN) ? U_w[row * HIDDEN + k0] : 0.f);
            u.y = (_Float16)((active && k1 < HIDDEN) ? U_w[row * HIDDEN + k1] : 0.f);
            Up[g][j] = u;
        }
    }

    float h = 0.f, c = 0.f;
    const float* __restrict__ xrow = x + (long)b * LSEQ;
    float* __restrict__ orow = out + (long)b * LSEQ;

    hb16[lane] = (_Float16)0.f;           // single wave: in-order LDS pipe
    __builtin_amdgcn_wave_barrier();      // compile-time ordering insurance

    const uint4* __restrict__ hbv = (const uint4*)hb16;  // 8 f16 per read

    // Prologue: group 0's x resident before the loop.
    float xg[UNROLL];
#pragma unroll
    for (int s = 0; s < UNROLL; ++s) xg[s] = xrow[s];

    for (int T = 0; T < LSEQ; T += UNROLL) {
        // Prefetch NEXT group's x now; consumed next iteration. Last group
        // prefetches row start (valid memory, values unused).
        const int Tn = (T + UNROLL < LSEQ) ? (T + UNROLL) : 0;
        float xn[UNROLL];
#pragma unroll
        for (int s = 0; s < UNROLL; ++s) xn[s] = xrow[Tn + s];

        float rsum[UNROLL];
#pragma unroll
        for (int s = 0; s < UNROLL; ++s) {
            // 7 same-address b128 broadcasts (conflict-free); scheduler
            // issues them first, DPP chain of step s-1 fills the wait.
            uint4 hq[7];
#pragma unroll
            for (int q = 0; q < 7; ++q) hq[q] = hbv[q];

            // Scalar fp32 accumulators seeded with x*W + (W_b+U_b);
            // 4 independent dot2 chains, depth 26 (issue-bound).
            float a0 = fmaf(xg[s], ww[0], bbias[0]);
            float a1 = fmaf(xg[s], ww[1], bbias[1]);
            float a2 = fmaf(xg[s], ww[2], bbias[2]);
            float a3 = fmaf(xg[s], ww[3], bbias[3]);
#pragma unroll
            for (int q = 0; q < 7; ++q) {
                const unsigned int wds[4] = {hq[q].x, hq[q].y, hq[q].z, hq[q].w};
#pragma unroll
                for (int e = 0; e < 4; ++e) {
                    const int j = 4 * q + e;          // k-pair index
                    if (j < 26) {
                        const half2_t hp = __builtin_bit_cast(half2_t, wds[e]);
                        a0 = FDOT2(hp, Up[0][j], a0);
                        a1 = FDOT2(hp, Up[1][j], a1);
                        a2 = FDOT2(hp, Up[2][j], a2);
                        a3 = FDOT2(hp, Up[3][j], a3);
                    }
                }
            }

            // NOTE: faithful to reference -- no sigmoid on gates.
            c = fmaf(a1, c, a0 * a2);     // c = gf*c + gi*gg
            h = a3 * fast_tanh(c);        // inactive lanes stay exactly 0

            __builtin_amdgcn_wave_barrier();  // reads above precede write
            hb16[lane] = (_Float16)h;         // 2B store; recurrence fp32
            __builtin_amdgcn_wave_barrier();  // write precedes next reads

            // Projection reduce in the broadcast-read shadow: pure VALU,
            // overlaps the ~120cy LDS window of step s+1's reads.
            rsum[s] = wave_reduce_to63(h * lw);
        }

        if (lane == 63) {
            float4 o0 = {rsum[0] + lb, rsum[1] + lb, rsum[2] + lb, rsum[3] + lb};
            float4 o1 = {rsum[4] + lb, rsum[5] + lb, rsum[6] + lb, rsum[7] + lb};
            *(float4*)&orow[T]     = o0;   // orow 16B-aligned (b*4000 bytes)
            *(float4*)&orow[T + 4] = o1;
        }

#pragma unroll
        for (int s = 0; s < UNROLL; ++s) xg[s] = xn[s];  // rotate buffers
    }
}

extern "C" void kernel_launch(void* const* d_in, const int* in_sizes, int n_in,
                              void* d_out, int out_size, void* d_ws, size_t ws_size,
                              hipStream_t stream) {
    const float* x     = (const float*)d_in[0];
    const float* W_w   = (const float*)d_in[1];
    const float* W_b   = (const float*)d_in[2];
    const float* U_w   = (const float*)d_in[3];
    const float* U_b   = (const float*)d_in[4];
    const float* lin_w = (const float*)d_in[5];
    const float* lin_b = (const float*)d_in[6];
    // d_in[7] = future (static 0; out_size == B*LSEQ)
    float* out = (float*)d_out;

    const int B = in_sizes[0] / LSEQ;  // 1024
    lstm_seq_kernel<<<dim3(B), dim3(64), 0, stream>>>(
        x, W_w, W_b, U_w, U_b, lin_w, lin_b, out);
}